// Round 6
// baseline (457.607 us; speedup 1.0000x reference)
//
#include <hip/hip_runtime.h>
#include <hip/hip_bf16.h>

#define NV 8192
#define FIN 128
#define FOUT 64

typedef __attribute__((ext_vector_type(8))) short short8;
typedef __attribute__((ext_vector_type(4))) float floatx4;

__device__ __forceinline__ uint f2bf_u(float f) {
  uint u = __float_as_uint(f);
  return (u + 0x7FFFu + ((u >> 16) & 1u)) >> 16;   // RTN-even bf16
}
__device__ __forceinline__ float bf2f(ushort b) {
  return __uint_as_float(((uint)b) << 16);
}

// ---------------------------------------------------------------------------
// Kernel 0: detect input dtype (fp32 vs packed bf16). flag=1 -> bf16 inputs.
// ---------------------------------------------------------------------------
__global__ void k0_detect(const uint* __restrict__ X, int* __restrict__ flag) {
  const int lane = threadIdx.x & 63;
  uint u = X[lane];
  uint e = (u >> 7) & 0xFF;
  bool ok = (e >= 100u) && (e <= 135u);
  unsigned long long b = __ballot(ok);
  if (lane == 0) *flag = (__builtin_popcountll(b) >= 48) ? 1 : 0;
}

// ---------------------------------------------------------------------------
// Kernel 1: h = X@W (MFMA) + s1/s2. h is written PRE-SWIZZLED into MFMA
// B-fragment order:  HtB[chunk][kc][nt][lane][8 bf16], 8 KB per 64-row chunk,
// where element (chunk,kc,nt,lane=q2*16+mcol,j) = h[chunk*64+kc*32+q2*8+j][nt*16+mcol].
// k1 block b covers h rows b*64..b*64+63 == chunk b exactly.
// ---------------------------------------------------------------------------
__global__ __launch_bounds__(256) void k1_proj(
    const void* __restrict__ Xv, const void* __restrict__ Wv,
    const void* __restrict__ a1v_, const void* __restrict__ a2v_,
    ushort* __restrict__ HtB, float* __restrict__ s1, float* __restrict__ s2,
    const int* __restrict__ flagp)
{
  const int is_bf16 = *flagp;
  const int wave = threadIdx.x >> 6;
  const int lane = threadIdx.x & 63;
  const int i0 = blockIdx.x * 64 + wave * 16;
  const int col = lane & 15;
  const int q   = lane >> 4;

  short8 bfrag[4][4];
  float a1f[4], a2f[4];
  if (is_bf16) {
    const ushort* W = (const ushort*)Wv;
#pragma unroll
    for (int nt = 0; nt < 4; ++nt)
#pragma unroll
      for (int kc = 0; kc < 4; ++kc) {
        short8 b;
#pragma unroll
        for (int j = 0; j < 8; ++j)
          b[j] = (short)W[(kc*32 + q*8 + j)*FOUT + nt*16 + col];
        bfrag[nt][kc] = b;
      }
#pragma unroll
    for (int nt = 0; nt < 4; ++nt) {
      a1f[nt] = bf2f(((const ushort*)a1v_)[nt*16 + col]);
      a2f[nt] = bf2f(((const ushort*)a2v_)[nt*16 + col]);
    }
  } else {
    const float* W = (const float*)Wv;
#pragma unroll
    for (int nt = 0; nt < 4; ++nt)
#pragma unroll
      for (int kc = 0; kc < 4; ++kc) {
        short8 b;
#pragma unroll
        for (int j = 0; j < 8; ++j)
          b[j] = (short)f2bf_u(W[(kc*32 + q*8 + j)*FOUT + nt*16 + col]);
        bfrag[nt][kc] = b;
      }
#pragma unroll
    for (int nt = 0; nt < 4; ++nt) {
      a1f[nt] = ((const float*)a1v_)[nt*16 + col];
      a2f[nt] = ((const float*)a2v_)[nt*16 + col];
    }
  }

  floatx4 acc[4] = {{0.f,0.f,0.f,0.f},{0.f,0.f,0.f,0.f},
                    {0.f,0.f,0.f,0.f},{0.f,0.f,0.f,0.f}};
#pragma unroll
  for (int kc = 0; kc < 4; ++kc) {
    short8 a;
    if (is_bf16) {
      a = *(const short8*)&((const ushort*)Xv)[(size_t)(i0 + col)*FIN + kc*32 + q*8];
    } else {
      const float* X = (const float*)Xv;
      float4 x0 = *(const float4*)&X[(size_t)(i0 + col)*FIN + kc*32 + q*8];
      float4 x1 = *(const float4*)&X[(size_t)(i0 + col)*FIN + kc*32 + q*8 + 4];
      a[0] = (short)f2bf_u(x0.x); a[1] = (short)f2bf_u(x0.y);
      a[2] = (short)f2bf_u(x0.z); a[3] = (short)f2bf_u(x0.w);
      a[4] = (short)f2bf_u(x1.x); a[5] = (short)f2bf_u(x1.y);
      a[6] = (short)f2bf_u(x1.z); a[7] = (short)f2bf_u(x1.w);
    }
#pragma unroll
    for (int nt = 0; nt < 4; ++nt)
      acc[nt] = __builtin_amdgcn_mfma_f32_16x16x32_bf16(a, bfrag[nt][kc], acc[nt], 0, 0, 0);
  }

  // ---- swizzled store into B-frag order ----
  // local h-row of reg: r_local = wave*16 + q*4 + reg (reg 0..3 contiguous,
  // same kc/q2 since r_local%8 in {0,4}). j0 = r_local0 & 7.
  const int r0  = wave*16 + q*4;
  const int kcH = r0 >> 5;
  const int q2  = (r0 >> 3) & 3;
  const int j0  = r0 & 7;
  ushort* chunkp = HtB + (size_t)blockIdx.x * 4096;

  float s1p[4] = {0,0,0,0}, s2p[4] = {0,0,0,0};
#pragma unroll
  for (int nt = 0; nt < 4; ++nt) {
    ushort4 pk;
    pk.x = (ushort)f2bf_u(acc[nt][0]);
    pk.y = (ushort)f2bf_u(acc[nt][1]);
    pk.z = (ushort)f2bf_u(acc[nt][2]);
    pk.w = (ushort)f2bf_u(acc[nt][3]);
    *(ushort4*)&chunkp[((kcH*4 + nt)*64 + q2*16 + col)*8 + j0] = pk;
#pragma unroll
    for (int reg = 0; reg < 4; ++reg) {
      s1p[reg] += acc[nt][reg] * a1f[nt];
      s2p[reg] += acc[nt][reg] * a2f[nt];
    }
  }
#pragma unroll
  for (int m = 1; m < 16; m <<= 1)
#pragma unroll
    for (int reg = 0; reg < 4; ++reg) {
      s1p[reg] += __shfl_xor(s1p[reg], m, 64);
      s2p[reg] += __shfl_xor(s2p[reg], m, 64);
    }
  if (col == 0)
#pragma unroll
    for (int reg = 0; reg < 4; ++reg) {
      s1[i0 + q*4 + reg] = s1p[reg];
      s2[i0 + q*4 + reg] = s2p[reg];
    }
}

// ---------------------------------------------------------------------------
// Kernel 2: barrier-free sweep. Per 16-row block, each of 4 waves owns a
// 64-col chunk of every 256-col tile (chunk = t*4+wave). P is wave-private
// LDS (within-wave ds order, no s_barrier). B-frags load straight from the
// pre-swizzled HtB: one dwordx4 per frag at base+lane*16 — coalesced, L2-hot.
// Next chunk's A/s2 are register-prefetched so HBM latency overlaps compute.
// One __syncthreads at the end to combine the 4 partial accumulators.
// ---------------------------------------------------------------------------
#define CT 256
#define NT (NV / CT)   // 32 tiles
#define PST 72         // 64+8 bf16; write b64 2-way (free), read b128 uniform

__global__ __launch_bounds__(256) void k2_attn(
    const int* __restrict__ A, const ushort* __restrict__ HtB,
    const float* __restrict__ s1g, const float* __restrict__ s2g,
    void* __restrict__ outv, const int* __restrict__ flagp)
{
  __shared__ __align__(16) ushort Pl[4][16 * PST];  //  9.2 KB wave-private P
  __shared__ __align__(16) float Red[4][16][64];    // 16   KB partial out
  __shared__ float Lw[4][16];

  const int is_bf16 = *flagp;
  const int tid  = threadIdx.x;
  const int wave = tid >> 6;
  const int lane = tid & 63;
  const int i0   = blockIdx.x * 16;
  const int q    = lane >> 4;
  const int mcol = lane & 15;

  ushort* Pw = &Pl[wave][0];

  float s1v[4];
#pragma unroll
  for (int rr = 0; rr < 4; ++rr) s1v[rr] = s1g[i0 + q*4 + rr];

  size_t arow[4];
#pragma unroll
  for (int rr = 0; rr < 4; ++rr)
    arow[rr] = (size_t)(i0 + q*4 + rr) * NV + mcol*4;

  float Lp[4] = {0,0,0,0};
  floatx4 acc[4] = {{0.f,0.f,0.f,0.f},{0.f,0.f,0.f,0.f},
                    {0.f,0.f,0.f,0.f},{0.f,0.f,0.f,0.f}};

  // ---- prefetch chunk 0 ----
  int4 av[4];
  float4 sv;
  {
    const int c = wave * 64;
#pragma unroll
    for (int rr = 0; rr < 4; ++rr) av[rr] = *(const int4*)&A[arow[rr] + c];
    sv = *(const float4*)&s2g[c + mcol*4];
  }

  for (int t = 0; t < NT; ++t) {
    const int c = t*CT + wave*64;
    // ---- prefetch next chunk (clamped at the tail; redundant last load) ----
    const int cn = (t + 1 < NT) ? (c + CT) : c;
    int4 nav[4];
    float4 nsv;
#pragma unroll
    for (int rr = 0; rr < 4; ++rr) nav[rr] = *(const int4*)&A[arow[rr] + cn];
    nsv = *(const float4*)&s2g[cn + mcol*4];

    // ---- exp + pack P (wave-private; no barrier) ----
#pragma unroll
    for (int rr = 0; rr < 4; ++rr) {
      const int4 a = av[rr];
      const float s1r = s1v[rr];
      float x0 = s1r + sv.x, x1 = s1r + sv.y, x2 = s1r + sv.z, x3 = s1r + sv.w;
      float w0 = a.x ? __expf(fmaxf(x0, 0.2f*x0)) : 0.f;
      float w1 = a.y ? __expf(fmaxf(x1, 0.2f*x1)) : 0.f;
      float w2 = a.z ? __expf(fmaxf(x2, 0.2f*x2)) : 0.f;
      float w3 = a.w ? __expf(fmaxf(x3, 0.2f*x3)) : 0.f;
      Lp[rr] += (w0 + w1) + (w2 + w3);
      uint2 pk;
      pk.x = f2bf_u(w0) | (f2bf_u(w1) << 16);
      pk.y = f2bf_u(w2) | (f2bf_u(w3) << 16);
      *(uint2*)&Pw[(q*4 + rr)*PST + mcol*4] = pk;
    }

    // ---- MFMA: A-frag from private P, B-frag from pre-swizzled HtB ----
    const size_t chb = (size_t)(t*4 + wave) * 4096;
#pragma unroll
    for (int kc2 = 0; kc2 < 2; ++kc2) {
      short8 af = *(const short8*)&Pw[mcol*PST + kc2*32 + q*8];
#pragma unroll
      for (int nt = 0; nt < 4; ++nt) {
        short8 bf = *(const short8*)&HtB[chb + ((kc2*4 + nt)*64 + lane)*8];
        acc[nt] = __builtin_amdgcn_mfma_f32_16x16x32_bf16(af, bf, acc[nt], 0, 0, 0);
      }
    }

#pragma unroll
    for (int rr = 0; rr < 4; ++rr) av[rr] = nav[rr];
    sv = nsv;
  }

  // ---- per-wave row sums: reduce over the 16 mcol lanes in each q group ----
#pragma unroll
  for (int m = 1; m < 16; m <<= 1)
#pragma unroll
    for (int rr = 0; rr < 4; ++rr) Lp[rr] += __shfl_xor(Lp[rr], m, 64);
  if (mcol == 0)
#pragma unroll
    for (int rr = 0; rr < 4; ++rr) Lw[wave][q*4 + rr] = Lp[rr];

  // partial accumulators to LDS (C/D layout: col=mcol, row=q*4+reg)
#pragma unroll
  for (int nt = 0; nt < 4; ++nt)
#pragma unroll
    for (int reg = 0; reg < 4; ++reg)
      Red[wave][q*4 + reg][nt*16 + mcol] = acc[nt][reg];

  __syncthreads();   // the only barrier

  // ---- combine + divide + store: r = tid>>4, features fb..fb+3 ----
  {
    const int r  = tid >> 4;
    const int fb = (tid & 15) * 4;
    float4 s = {0.f, 0.f, 0.f, 0.f};
    float L = 0.f;
#pragma unroll
    for (int w = 0; w < 4; ++w) {
      float4 v = *(const float4*)&Red[w][r][fb];
      s.x += v.x; s.y += v.y; s.z += v.z; s.w += v.w;
      L += Lw[w][r];
    }
    const float inv = __frcp_rn(L);
    s.x *= inv; s.y *= inv; s.z *= inv; s.w *= inv;
    if (is_bf16) {
      ushort4 pk;
      pk.x = (ushort)f2bf_u(s.x); pk.y = (ushort)f2bf_u(s.y);
      pk.z = (ushort)f2bf_u(s.z); pk.w = (ushort)f2bf_u(s.w);
      *(ushort4*)&((ushort*)outv)[(size_t)(i0 + r)*FOUT + fb] = pk;
    } else {
      *(float4*)&((float*)outv)[(size_t)(i0 + r)*FOUT + fb] = s;
    }
  }
}

extern "C" void kernel_launch(void* const* d_in, const int* in_sizes, int n_in,
                              void* d_out, int out_size, void* d_ws, size_t ws_size,
                              hipStream_t stream) {
  const void* X  = d_in[0];                 // f32 (or bf16) [8192][128]
  const int*  A  = (const int*)d_in[1];     // int32 [8192][8192]
  const void* W  = d_in[2];                 // f32 (or bf16) [128][64]
  const void* a1 = d_in[3];                 // f32 (or bf16) [64]
  const void* a2 = d_in[4];                 // f32 (or bf16) [64]

  char* ws = (char*)d_ws;
  ushort* HtB  = (ushort*)ws;                        // 128 chunks x 8 KB = 1 MiB
  float*  s1   = (float*)(ws + (size_t)FOUT*NV*2);   // 32 KiB
  float*  s2   = s1 + NV;                            // 32 KiB
  int*    flag = (int*)(s2 + NV);                    // 4 B

  hipLaunchKernelGGL(k0_detect, dim3(1), dim3(64), 0, stream,
                     (const uint*)X, flag);
  hipLaunchKernelGGL(k1_proj, dim3(NV/64), dim3(256), 0, stream,
                     X, W, a1, a2, HtB, s1, s2, flag);
  hipLaunchKernelGGL(k2_attn, dim3(NV/16), dim3(256), 0, stream,
                     A, HtB, s1, s2, d_out, flag);
}

// Round 7
// 368.308 us; speedup vs baseline: 1.2425x; 1.2425x over previous
//
#include <hip/hip_runtime.h>
#include <hip/hip_bf16.h>

#define NV 8192
#define FIN 128
#define FOUT 64

typedef __attribute__((ext_vector_type(8))) short short8;
typedef __attribute__((ext_vector_type(4))) float floatx4;

__device__ __forceinline__ uint f2bf_u(float f) {
  uint u = __float_as_uint(f);
  return (u + 0x7FFFu + ((u >> 16) & 1u)) >> 16;   // RTN-even bf16
}
__device__ __forceinline__ float bf2f(ushort b) {
  return __uint_as_float(((uint)b) << 16);
}

// ---------------------------------------------------------------------------
// Kernel 0: detect input dtype (fp32 vs packed bf16). flag=1 -> bf16 inputs.
// ---------------------------------------------------------------------------
__global__ void k0_detect(const uint* __restrict__ X, int* __restrict__ flag) {
  const int lane = threadIdx.x & 63;
  uint u = X[lane];
  uint e = (u >> 7) & 0xFF;
  bool ok = (e >= 100u) && (e <= 135u);
  unsigned long long b = __ballot(ok);
  if (lane == 0) *flag = (__builtin_popcountll(b) >= 48) ? 1 : 0;
}

// ---------------------------------------------------------------------------
// Kernel 1: h = X@W (MFMA), write Ht (bf16, [64][8192]) + s1/s2 (fp32).
// (R5 version — proven)
// ---------------------------------------------------------------------------
__global__ __launch_bounds__(256) void k1_proj(
    const void* __restrict__ Xv, const void* __restrict__ Wv,
    const void* __restrict__ a1v_, const void* __restrict__ a2v_,
    ushort* __restrict__ HtT, float* __restrict__ s1, float* __restrict__ s2,
    const int* __restrict__ flagp)
{
  const int is_bf16 = *flagp;
  const int wave = threadIdx.x >> 6;
  const int lane = threadIdx.x & 63;
  const int i0 = blockIdx.x * 64 + wave * 16;
  const int col = lane & 15;
  const int q   = lane >> 4;

  short8 bfrag[4][4];
  float a1f[4], a2f[4];
  if (is_bf16) {
    const ushort* W = (const ushort*)Wv;
#pragma unroll
    for (int nt = 0; nt < 4; ++nt)
#pragma unroll
      for (int kc = 0; kc < 4; ++kc) {
        short8 b;
#pragma unroll
        for (int j = 0; j < 8; ++j)
          b[j] = (short)W[(kc*32 + q*8 + j)*FOUT + nt*16 + col];
        bfrag[nt][kc] = b;
      }
#pragma unroll
    for (int nt = 0; nt < 4; ++nt) {
      a1f[nt] = bf2f(((const ushort*)a1v_)[nt*16 + col]);
      a2f[nt] = bf2f(((const ushort*)a2v_)[nt*16 + col]);
    }
  } else {
    const float* W = (const float*)Wv;
#pragma unroll
    for (int nt = 0; nt < 4; ++nt)
#pragma unroll
      for (int kc = 0; kc < 4; ++kc) {
        short8 b;
#pragma unroll
        for (int j = 0; j < 8; ++j)
          b[j] = (short)f2bf_u(W[(kc*32 + q*8 + j)*FOUT + nt*16 + col]);
        bfrag[nt][kc] = b;
      }
#pragma unroll
    for (int nt = 0; nt < 4; ++nt) {
      a1f[nt] = ((const float*)a1v_)[nt*16 + col];
      a2f[nt] = ((const float*)a2v_)[nt*16 + col];
    }
  }

  floatx4 acc[4] = {{0.f,0.f,0.f,0.f},{0.f,0.f,0.f,0.f},
                    {0.f,0.f,0.f,0.f},{0.f,0.f,0.f,0.f}};
#pragma unroll
  for (int kc = 0; kc < 4; ++kc) {
    short8 a;
    if (is_bf16) {
      a = *(const short8*)&((const ushort*)Xv)[(size_t)(i0 + col)*FIN + kc*32 + q*8];
    } else {
      const float* X = (const float*)Xv;
      float4 x0 = *(const float4*)&X[(size_t)(i0 + col)*FIN + kc*32 + q*8];
      float4 x1 = *(const float4*)&X[(size_t)(i0 + col)*FIN + kc*32 + q*8 + 4];
      a[0] = (short)f2bf_u(x0.x); a[1] = (short)f2bf_u(x0.y);
      a[2] = (short)f2bf_u(x0.z); a[3] = (short)f2bf_u(x0.w);
      a[4] = (short)f2bf_u(x1.x); a[5] = (short)f2bf_u(x1.y);
      a[6] = (short)f2bf_u(x1.z); a[7] = (short)f2bf_u(x1.w);
    }
#pragma unroll
    for (int nt = 0; nt < 4; ++nt)
      acc[nt] = __builtin_amdgcn_mfma_f32_16x16x32_bf16(a, bfrag[nt][kc], acc[nt], 0, 0, 0);
  }

  float s1p[4] = {0,0,0,0}, s2p[4] = {0,0,0,0};
#pragma unroll
  for (int nt = 0; nt < 4; ++nt) {
    ushort4 pk;
    pk.x = (ushort)f2bf_u(acc[nt][0]);
    pk.y = (ushort)f2bf_u(acc[nt][1]);
    pk.z = (ushort)f2bf_u(acc[nt][2]);
    pk.w = (ushort)f2bf_u(acc[nt][3]);
    *(ushort4*)&HtT[(size_t)(nt*16 + col)*NV + i0 + q*4] = pk;
#pragma unroll
    for (int reg = 0; reg < 4; ++reg) {
      s1p[reg] += acc[nt][reg] * a1f[nt];
      s2p[reg] += acc[nt][reg] * a2f[nt];
    }
  }
#pragma unroll
  for (int m = 1; m < 16; m <<= 1)
#pragma unroll
    for (int reg = 0; reg < 4; ++reg) {
      s1p[reg] += __shfl_xor(s1p[reg], m, 64);
      s2p[reg] += __shfl_xor(s2p[reg], m, 64);
    }
  if (col == 0)
#pragma unroll
    for (int reg = 0; reg < 4; ++reg) {
      s1[i0 + q*4 + reg] = s1p[reg];
      s2[i0 + q*4 + reg] = s2p[reg];
    }
}

// ---------------------------------------------------------------------------
// Kernel 2 (R5 staged structure + per-block COLUMN-PHASE STAGGER):
// A-row stride is 32 KB ≡ 0 mod the HBM channel interleave, so blocks that
// sweep columns in lockstep all hit the same few channels at any instant.
// Block b starts its (order-independent) tile sweep at phase (b*23)&63,
// spreading the instantaneous footprint over all channels.
// ---------------------------------------------------------------------------
#define CT 128
#define NT (NV / CT)       // 64 tiles
#define PST 136            // 128+8 bf16; 272 B row stride, uniform banks

__global__ __launch_bounds__(256, 6) void k2_attn(
    const int* __restrict__ A, const ushort* __restrict__ HtT,
    const float* __restrict__ s1g, const float* __restrict__ s2g,
    void* __restrict__ outv, const int* __restrict__ flagp)
{
  __shared__ __align__(16) ushort Pl[16 * PST];   //  4.25 KB
  __shared__ __align__(16) ushort Hl[64 * PST];   // 17    KB
  __shared__ float Lrow[16];

  const int is_bf16 = *flagp;
  const int tid  = threadIdx.x;
  const int wave = tid >> 6;
  const int lane = tid & 63;
  const int i0   = blockIdx.x * 16;
  const int q    = lane >> 4;
  const int mcol = lane & 15;
  const int r    = tid >> 4;        // 0..15: row this thread exp-processes
  const int cb   = (tid & 15) * 8;  // col offset in tile (8 cols/thread)
  const int t0   = (blockIdx.x * 23) & (NT - 1);   // column-phase stagger

  const float s1r = s1g[i0 + r];
  const size_t abase = (size_t)(i0 + r) * NV + cb;

  float Lp = 0.f;
  floatx4 acc = {0.f, 0.f, 0.f, 0.f};

  // ---- prefetch first tile (phase t0) ----
  {
    const int c = t0 * CT;
    int4 av0_ = *(const int4*)&A[abase + c];
    int4 av1_ = *(const int4*)&A[abase + c + 4];
    float4 sv0_ = *(const float4*)&s2g[c + cb];
    float4 sv1_ = *(const float4*)&s2g[c + cb + 4];
    short8 hv_[4];
#pragma unroll
    for (int it = 0; it < 4; ++it)
      hv_[it] = *(const short8*)&HtT[(size_t)(r + 16*it) * NV + c + cb];
    // fallthrough into loop via registers below
    int4 av0 = av0_, av1 = av1_;
    float4 sv0 = sv0_, sv1 = sv1_;
    short8 hv[4] = {hv_[0], hv_[1], hv_[2], hv_[3]};

    for (int t = 0; t < NT; ++t) {
      __syncthreads();   // Pl/Hl free (prev MFMA done); drains prefetch vmem

      // ---- stage: exp + pack P, copy Ht tile ----
      {
        float x0 = s1r + sv0.x, x1 = s1r + sv0.y, x2 = s1r + sv0.z, x3 = s1r + sv0.w;
        float x4 = s1r + sv1.x, x5 = s1r + sv1.y, x6 = s1r + sv1.z, x7 = s1r + sv1.w;
        float w0 = av0.x ? __expf(fmaxf(x0, 0.2f*x0)) : 0.f;
        float w1 = av0.y ? __expf(fmaxf(x1, 0.2f*x1)) : 0.f;
        float w2 = av0.z ? __expf(fmaxf(x2, 0.2f*x2)) : 0.f;
        float w3 = av0.w ? __expf(fmaxf(x3, 0.2f*x3)) : 0.f;
        float w4 = av1.x ? __expf(fmaxf(x4, 0.2f*x4)) : 0.f;
        float w5 = av1.y ? __expf(fmaxf(x5, 0.2f*x5)) : 0.f;
        float w6 = av1.z ? __expf(fmaxf(x6, 0.2f*x6)) : 0.f;
        float w7 = av1.w ? __expf(fmaxf(x7, 0.2f*x7)) : 0.f;
        Lp += ((w0 + w1) + (w2 + w3)) + ((w4 + w5) + (w6 + w7));
        uint4 pk;
        pk.x = f2bf_u(w0) | (f2bf_u(w1) << 16);
        pk.y = f2bf_u(w2) | (f2bf_u(w3) << 16);
        pk.z = f2bf_u(w4) | (f2bf_u(w5) << 16);
        pk.w = f2bf_u(w6) | (f2bf_u(w7) << 16);
        *(uint4*)&Pl[r * PST + cb] = pk;
#pragma unroll
        for (int it = 0; it < 4; ++it)
          *(short8*)&Hl[(r + 16*it) * PST + cb] = hv[it];
      }

      __syncthreads();   // publish

      // ---- prefetch next tile (flies across the MFMA phase) ----
      if (t + 1 < NT) {
        const int c2 = ((t + 1 + t0) & (NT - 1)) * CT;
        av0 = *(const int4*)&A[abase + c2];
        av1 = *(const int4*)&A[abase + c2 + 4];
        sv0 = *(const float4*)&s2g[c2 + cb];
        sv1 = *(const float4*)&s2g[c2 + cb + 4];
#pragma unroll
        for (int it = 0; it < 4; ++it)
          hv[it] = *(const short8*)&HtT[(size_t)(r + 16*it) * NV + c2 + cb];
      }

      // ---- MFMA: wave w computes out[0:16, w*16:(w+1)*16] ----
#pragma unroll
      for (int kc = 0; kc < 4; ++kc) {
        short8 af = *(const short8*)&Pl[mcol * PST + kc*32 + q*8];
        short8 bf = *(const short8*)&Hl[(wave*16 + mcol) * PST + kc*32 + q*8];
        acc = __builtin_amdgcn_mfma_f32_16x16x32_bf16(af, bf, acc, 0, 0, 0);
      }
    }
  }

  // ---- denominators: reduce Lp over the 16 lanes sharing row r ----
#pragma unroll
  for (int m = 1; m < 16; m <<= 1) Lp += __shfl_xor(Lp, m, 64);
  if (mcol == 0) Lrow[r] = Lp;
  __syncthreads();

  // ---- epilogue: divide + store. C/D: col=mcol, row=q*4+reg ----
#pragma unroll
  for (int reg = 0; reg < 4; ++reg) {
    int rr = q*4 + reg;
    float v = acc[reg] / Lrow[rr];
    if (is_bf16)
      ((ushort*)outv)[(size_t)(i0 + rr)*FOUT + wave*16 + mcol] = (ushort)f2bf_u(v);
    else
      ((float*)outv)[(size_t)(i0 + rr)*FOUT + wave*16 + mcol] = v;
  }
}

extern "C" void kernel_launch(void* const* d_in, const int* in_sizes, int n_in,
                              void* d_out, int out_size, void* d_ws, size_t ws_size,
                              hipStream_t stream) {
  const void* X  = d_in[0];                 // f32 (or bf16) [8192][128]
  const int*  A  = (const int*)d_in[1];     // int32 [8192][8192]
  const void* W  = d_in[2];                 // f32 (or bf16) [128][64]
  const void* a1 = d_in[3];                 // f32 (or bf16) [64]
  const void* a2 = d_in[4];                 // f32 (or bf16) [64]

  char* ws = (char*)d_ws;
  ushort* HtT  = (ushort*)ws;                        // 1 MiB
  float*  s1   = (float*)(ws + (size_t)FOUT*NV*2);   // 32 KiB
  float*  s2   = s1 + NV;                            // 32 KiB
  int*    flag = (int*)(s2 + NV);                    // 4 B

  hipLaunchKernelGGL(k0_detect, dim3(1), dim3(64), 0, stream,
                     (const uint*)X, flag);
  hipLaunchKernelGGL(k1_proj, dim3(NV/64), dim3(256), 0, stream,
                     X, W, a1, a2, HtT, s1, s2, flag);
  hipLaunchKernelGGL(k2_attn, dim3(NV/16), dim3(256), 0, stream,
                     A, HtT, s1, s2, d_out, flag);
}